// Round 14
// baseline (44.107 us; speedup 1.0000x reference)
//
#include <hip/hip_runtime.h>
#include <cmath>

// Problem constants
#define BROWS 32768
#define SLEN  1024
#define TAILW 195
#define NB1   8192            // rows kernel: 8192 blocks x 4 waves = 32768 waves, 1 row/wave
#define NB2   128             // rowfin: 128 blocks x 256 threads, 1 row/thread
#define PSTRIDE 128           // partials [7][128]

__device__ __constant__ float c_decay_taus[4] = {40.0f, 300.0f, 230.0f, 2.4f};
__device__ __constant__ float c_rise_taus[4]  = {5.0f, 20.0f, 10.0f, 2.0f};

typedef float v2f __attribute__((ext_vector_type(2)));

// Per-row stats, 32 B.
struct alignas(16) RowStat {
    unsigned nSk;   // n | (Sk<<16)
    unsigned Skk;
    float    csum;
    unsigned pki;   // (peak<<22)|(i10<<11)|i90
    double   Sy;
    double   Sky;
};

// ---- DPP wave-reduction helpers (pure VALU, no DS unit, no SALU) ----
template<int CTRL>
__device__ __forceinline__ unsigned dpp0_u32(unsigned x) {
    return (unsigned)__builtin_amdgcn_update_dpp(0, (int)x, CTRL, 0xf, 0xf, true);
}
template<int CTRL>
__device__ __forceinline__ unsigned dppid_u32(unsigned x) {
    return (unsigned)__builtin_amdgcn_update_dpp((int)x, (int)x, CTRL, 0xf, 0xf, false);
}
template<int CTRL>
__device__ __forceinline__ float dpp0_f32(float x) {
    return __int_as_float(
        __builtin_amdgcn_update_dpp(0, __float_as_int(x), CTRL, 0xf, 0xf, true));
}
template<int CTRL>
__device__ __forceinline__ float dppid_f32(float x) {
    return __int_as_float(__builtin_amdgcn_update_dpp(
        __float_as_int(x), __float_as_int(x), CTRL, 0xf, 0xf, false));
}
template<int CTRL>
__device__ __forceinline__ double dpp0_f64(double x) {
    const int lo = __builtin_amdgcn_update_dpp(0, __double2loint(x), CTRL, 0xf, 0xf, true);
    const int hi = __builtin_amdgcn_update_dpp(0, __double2hiint(x), CTRL, 0xf, 0xf, true);
    return __hiloint2double(hi, lo);
}
#define ROW_SHR1  0x111
#define ROW_SHR2  0x112
#define ROW_SHR4  0x114
#define ROW_SHR8  0x118
#define BCAST15   0x142
#define BCAST31   0x143
#define WSUM_F32(x) { x += dpp0_f32<ROW_SHR1>(x); x += dpp0_f32<ROW_SHR2>(x); \
                      x += dpp0_f32<ROW_SHR4>(x); x += dpp0_f32<ROW_SHR8>(x); \
                      x += dpp0_f32<BCAST15>(x);  x += dpp0_f32<BCAST31>(x); }
#define WSUM_U32(x) { x += dpp0_u32<ROW_SHR1>(x); x += dpp0_u32<ROW_SHR2>(x); \
                      x += dpp0_u32<ROW_SHR4>(x); x += dpp0_u32<ROW_SHR8>(x); \
                      x += dpp0_u32<BCAST15>(x);  x += dpp0_u32<BCAST31>(x); }
#define WSUM_F64(x) { x += dpp0_f64<ROW_SHR1>(x); x += dpp0_f64<ROW_SHR2>(x); \
                      x += dpp0_f64<ROW_SHR4>(x); x += dpp0_f64<ROW_SHR8>(x); \
                      x += dpp0_f64<BCAST15>(x);  x += dpp0_f64<BCAST31>(x); }
#define WMAX_F32(x) { x = fmaxf(x, dppid_f32<ROW_SHR1>(x)); x = fmaxf(x, dppid_f32<ROW_SHR2>(x)); \
                      x = fmaxf(x, dppid_f32<ROW_SHR4>(x)); x = fmaxf(x, dppid_f32<ROW_SHR8>(x)); \
                      x = fmaxf(x, dppid_f32<BCAST15>(x));  x = fmaxf(x, dppid_f32<BCAST31>(x)); }
#define WMIN_U32(x) { x = min(x, dppid_u32<ROW_SHR1>(x)); x = min(x, dppid_u32<ROW_SHR2>(x)); \
                      x = min(x, dppid_u32<ROW_SHR4>(x)); x = min(x, dppid_u32<ROW_SHR8>(x)); \
                      x = min(x, dppid_u32<BCAST15>(x));  x = min(x, dppid_u32<BCAST31>(x)); }

// Kernel 1: waveform-only, one row per wave. ALL reductions and index-finding
// via per-lane VALU + DPP chains — no ballots, no SALU round-trips, no
// early-exit branches in the hot path. Kernel kept free of extra side-effects
// (r6/r10/r11: coupling stores/atomics into this kernel collapses hipcc
// regalloc to 24-32 VGPR and serializes the loads, ~7x slower).
extern "C" __global__ __launch_bounds__(256, 8)
void physics_rows(const float* __restrict__ wave, RowStat* __restrict__ stats)
{
    const int lane = threadIdx.x & 63;
    const int row  = (blockIdx.x * 256 + (int)threadIdx.x) >> 6;   // 1 row per wave
    const int lane4 = lane * 4;
    const float4* p = reinterpret_cast<const float4*>(wave) + (size_t)row * (SLEN / 4) + lane;

    const float4 c0 = p[0], c1 = p[64], c2 = p[128], c3 = p[192];
    float vals[16] = {c0.x,c0.y,c0.z,c0.w, c1.x,c1.y,c1.z,c1.w,
                      c2.x,c2.y,c2.z,c2.w, c3.x,c3.y,c3.z,c3.w};

    // ---- pass 1: per-lane value-max (max3 tree) + relu-sum (packed f32) ----
    float m0 = fmaxf(fmaxf(vals[0],  vals[1]),  vals[2]);
    float m1 = fmaxf(fmaxf(vals[3],  vals[4]),  vals[5]);
    float m2 = fmaxf(fmaxf(vals[6],  vals[7]),  vals[8]);
    float m3 = fmaxf(fmaxf(vals[9],  vals[10]), vals[11]);
    float m4 = fmaxf(fmaxf(vals[12], vals[13]), fmaxf(vals[14], vals[15]));
    float bm = fmaxf(fmaxf(fmaxf(m0, m1), m2), fmaxf(m3, m4));

    v2f sa = {0.f, 0.f}, sb = {0.f, 0.f};
    #pragma unroll
    for (int k = 0; k < 16; k += 4) {
        v2f p0 = {vals[k],     vals[k + 1]};
        v2f p1 = {vals[k + 2], vals[k + 3]};
        sa += __builtin_elementwise_max(p0, (v2f){0.f, 0.f});
        sb += __builtin_elementwise_max(p1, (v2f){0.f, 0.f});
    }
    const v2f sab = sa + sb;
    float csum = sab.x + sab.y;

    // ---- DPP wave reductions: amp (max) + csum (sum, valid lane 63) ----
    WMAX_F32(bm);
    WSUM_F32(csum);
    const float amp = __int_as_float(
        __builtin_amdgcn_readlane(__float_as_int(bm), 63));

    // ---- peak: per-lane index-min of matches -> DPP u32 min (branch-free) ----
    unsigned pidx = SLEN;
    #pragma unroll
    for (int k = 0; k < 16; ++k) {
        const unsigned j = (unsigned)((k >> 2) * 256 + lane4 + (k & 3));
        if (vals[k] == amp) pidx = min(pidx, j);   // cndmask chain, j asc in k
    }
    WMIN_U32(pidx);
    const int peak = __builtin_amdgcn_readlane((int)pidx, 63);   // uniform
    const bool do_decay = (peak < SLEN - 20);
    const int  pm5 = peak + 5;

    // ---- rise crossings: per-lane masked index-min -> 2 DPP min chains ----
    const float t10v = 0.1f * amp, t90v = 0.9f * amp;
    unsigned i10v = SLEN, i90v = SLEN;
    #pragma unroll
    for (int k = 0; k < 16; ++k) {
        const int j = (k >> 2) * 256 + lane4 + (k & 3);
        const float w = vals[k];
        const bool edge = (j < peak);
        if (edge && w >= t10v) i10v = min(i10v, (unsigned)j);
        if (edge && w >= t90v) i90v = min(i90v, (unsigned)j);
    }
    WMIN_U32(i10v);
    WMIN_U32(i90v);
    // consumed only by lane 63's store — no broadcast needed

    // ---- decay: f64 y-sums + per-lane cnt; all reduced via DPP chains ----
    double Sy = 0.0, Sky = 0.0;
    unsigned cnt = 0;
    if (do_decay) {                        // uniform
        #pragma unroll
        for (int q = 0; q < 4; ++q) {
            if (q * 256 + 255 >= pm5 && q * 256 <= pm5 + (TAILW - 1)) {  // uniform
                #pragma unroll
                for (int r = 0; r < 4; ++r) {
                    const int kk = q * 256 + lane4 + r - pm5;
                    const float w = vals[q * 4 + r];
                    const bool cond = ((unsigned)kk < (unsigned)TAILW) && (w > 0.0f);
                    const float ym = cond ? __logf(w + 1e-8f) : 0.0f;  // native log
                    cnt += cond ? 1u : 0u;
                    const double y64 = (double)ym;     // masked lanes add +0.0
                    Sy += y64;
                    Sky = fma((double)kk, y64, Sky);
                }
            }
        }
    }
    WSUM_F64(Sy);
    WSUM_F64(Sky);
    WSUM_U32(cnt);
    const int cntT = __builtin_amdgcn_readlane((int)cnt, 63);    // uniform

    // n/Sk/Skk: closed form when all L window samples positive (cntT==L)
    unsigned out_nSk = 0, out_Skk = 0;
    if (do_decay) {
        const int L = min(TAILW, SLEN - pm5);
        if (cntT == L) {                   // common case: uniform SALU math
            const unsigned uL = (unsigned)L;
            const unsigned Sk = uL * (uL - 1u) / 2u;
            out_nSk = uL | (Sk << 16);
            out_Skk = (uL - 1u) * uL * (2u * uL - 1u) / 6u;
        } else {                           // rare (exact zeros in tail): recompute
            unsigned nSk_p = 0, Skk = 0;
            #pragma unroll
            for (int q = 0; q < 4; ++q) {
                if (q * 256 + 255 >= pm5 && q * 256 <= pm5 + (TAILW - 1)) {
                    #pragma unroll
                    for (int r = 0; r < 4; ++r) {
                        const int kk = q * 256 + lane4 + r - pm5;
                        const float w = vals[q * 4 + r];
                        if (((unsigned)kk < (unsigned)TAILW) && (w > 0.0f)) {
                            nSk_p += 1u + ((unsigned)kk << 8);
                            Skk   += (unsigned)(kk * kk);
                        }
                    }
                }
            }
            WSUM_U32(nSk_p);
            WSUM_U32(Skk);
            out_nSk = (nSk_p & 0xFFu) | ((nSk_p >> 8) << 16);  // valid in lane 63
            out_Skk = Skk;
        }
    }

    if (lane == 63) {
        RowStat st;
        st.nSk  = out_nSk;
        st.Skk  = out_Skk;
        st.csum = csum;
        st.pki  = ((unsigned)peak << 22) | (i10v << 11) | i90v;
        st.Sy   = Sy;
        st.Sky  = Sky;
        stats[row] = st;
    }
}

// Kernel 2: one thread per row epilogue + block partials + last-block final
// reduce (atomic-counter pattern).
extern "C" __global__ __launch_bounds__(256)
void physics_rowfin(const RowStat* __restrict__ stats,
                    const float* __restrict__ logits,
                    const int* __restrict__ labels,
                    const float* __restrict__ amps,
                    double* __restrict__ partials,     // [7][PSTRIDE]
                    unsigned* __restrict__ counter,    // zeroed by memset each launch
                    float* __restrict__ out)
{
    const int r    = blockIdx.x * 256 + threadIdx.x;   // always < BROWS
    const int lane = threadIdx.x & 63;
    const int wid  = threadIdx.x >> 6;

    __shared__ double sm[4][7];
    __shared__ int s_last;

    const RowStat st = stats[r];
    const unsigned n_u  = st.nSk & 0xFFFFu;
    const unsigned Sk_u = st.nSk >> 16;
    const int peak = (int)(st.pki >> 22);
    const int i10  = (int)((st.pki >> 11) & 0x7FFu);
    const int i90  = (int)(st.pki & 0x7FFu);

    // CE + predicted class (library expf/logf — accuracy matters here)
    const float4 l4 = reinterpret_cast<const float4*>(logits)[r];
    float lg[4] = {l4.x, l4.y, l4.z, l4.w};
    int pred = 0; float pbest = lg[0];
    #pragma unroll
    for (int c = 1; c < 4; ++c) if (lg[c] > pbest) { pbest = lg[c]; pred = c; }
    const float m = fmaxf(fmaxf(lg[0], lg[1]), fmaxf(lg[2], lg[3]));
    const float sexp = expf(lg[0] - m) + expf(lg[1] - m)
                     + expf(lg[2] - m) + expf(lg[3] - m);
    const float lse = m + logf(sexp);
    const double v0 = (double)(lse - lg[labels[r]]);

    // decay loss (f64 combine — slope/tau cancellation-sensitive)
    double v1 = 0.0, v2 = 0.0;
    if (peak < SLEN - 20 && n_u >= 5u) {
        const double dn  = (double)n_u;
        const double dSk = (double)Sk_u;
        const double num = st.Sky - dSk * st.Sy / dn;           // DT_NS factored out
        const double den = 8.0 * ((double)st.Skk - dSk * dSk / dn);
        if (den > 0.0) {
            const double slope = num / fmax(den, 1e-30);
            const double tau   = -1.0 / (slope + 1e-8);
            const double d     = tau - (double)c_decay_taus[pred];
            v1 = d * d; v2 = 1.0;
        }
    }
    // rise loss
    double v3 = 0.0, v4 = 0.0;
    if (peak >= 10 && i10 < SLEN && i90 < SLEN) {
        const float rise = (float)(i90 - i10) * 8.0f;
        const float er   = c_rise_taus[pred];
        v3 = (double)(fabsf(rise - er) / er); v4 = 1.0;
    }
    // energy ratio moments
    const double ratio = (double)st.csum / ((double)amps[r] + 1e-8);

    double v[7] = {v0, v1, v2, v3, v4, ratio, ratio * ratio};
    #pragma unroll
    for (int i = 0; i < 7; ++i) {
        #pragma unroll
        for (int off = 1; off < 64; off <<= 1)
            v[i] += __shfl_xor(v[i], off, 64);
    }
    if (lane == 0) {
        #pragma unroll
        for (int i = 0; i < 7; ++i) sm[wid][i] = v[i];
    }
    __syncthreads();
    if (threadIdx.x < 7) {
        const int i = threadIdx.x;
        const double t = sm[0][i] + sm[1][i] + sm[2][i] + sm[3][i];
        __hip_atomic_store(&partials[(size_t)i * PSTRIDE + blockIdx.x], t,
                           __ATOMIC_RELAXED, __HIP_MEMORY_SCOPE_AGENT);
    }
    __syncthreads();
    if (threadIdx.x == 0) {
        const unsigned prev = __hip_atomic_fetch_add(counter, 1u,
                                  __ATOMIC_ACQ_REL, __HIP_MEMORY_SCOPE_AGENT);
        s_last = (prev == NB2 - 1) ? 1 : 0;
    }
    __syncthreads();
    if (!s_last) return;

    // ---- last block: reduce [7][128] partials, write the 5 outputs ----
    double loc[7] = {0, 0, 0, 0, 0, 0, 0};
    if (threadIdx.x < PSTRIDE) {
        #pragma unroll
        for (int i = 0; i < 7; ++i)
            loc[i] = __hip_atomic_load(&partials[(size_t)i * PSTRIDE + threadIdx.x],
                                       __ATOMIC_RELAXED, __HIP_MEMORY_SCOPE_AGENT);
    }
    #pragma unroll
    for (int i = 0; i < 7; ++i) {
        #pragma unroll
        for (int off = 1; off < 64; off <<= 1)
            loc[i] += __shfl_xor(loc[i], off, 64);
    }
    __syncthreads();                       // reuse sm safely
    if (lane == 0 && wid < 2) {
        #pragma unroll
        for (int i = 0; i < 7; ++i) sm[wid][i] = loc[i];
    }
    __syncthreads();
    if (threadIdx.x == 0) {
        double t[7];
        #pragma unroll
        for (int i = 0; i < 7; ++i) t[i] = sm[0][i] + sm[1][i];
        const double Bn = (double)BROWS;
        const double ce    = t[0] / Bn;
        const double decay = (t[2] > 0.0) ? t[1] / fmax(t[2], 1.0) : 0.0;
        const double rise  = (t[4] > 0.0) ? t[3] / fmax(t[4], 1.0) : 0.0;
        const double var   = (t[6] - t[5] * t[5] / Bn) / (Bn - 1.0);  // ddof=1
        const double total = 0.7 * ce + 0.2 * decay + 0.1 * var + 0.05 * rise;
        out[0] = (float)total; out[1] = (float)ce; out[2] = (float)decay;
        out[3] = (float)var;   out[4] = (float)rise;
    }
}

extern "C" void kernel_launch(void* const* d_in, const int* in_sizes, int n_in,
                              void* d_out, int out_size, void* d_ws, size_t ws_size,
                              hipStream_t stream) {
    const float* logits = (const float*)d_in[0];
    const int*   labels = (const int*)d_in[1];
    const float* wave   = (const float*)d_in[2];
    const float* amps   = (const float*)d_in[3];

    RowStat*  stats    = (RowStat*)d_ws;                                  // 1 MiB
    double*   partials = (double*)((char*)d_ws + (size_t)BROWS * sizeof(RowStat));
    unsigned* counter  = (unsigned*)((char*)partials + 7 * PSTRIDE * sizeof(double));

    hipMemsetAsync(counter, 0, sizeof(unsigned), stream);
    physics_rows<<<NB1, 256, 0, stream>>>(wave, stats);
    physics_rowfin<<<NB2, 256, 0, stream>>>(stats, logits, labels, amps,
                                            partials, counter, (float*)d_out);
}

// Round 15
// 41.186 us; speedup vs baseline: 1.0709x; 1.0709x over previous
//
#include <hip/hip_runtime.h>
#include <cmath>

// Problem constants
#define BROWS 32768
#define SLEN  1024
#define TAILW 195
#define NB1   8192            // rows kernel: 8192 blocks x 4 waves = 32768 waves, 1 row/wave
#define NB2   256             // rowfin: 256 blocks x 128 threads, 1 row/thread
#define PSTRIDE 256           // partials [7][256]

__device__ __constant__ float c_decay_taus[4] = {40.0f, 300.0f, 230.0f, 2.4f};
__device__ __constant__ float c_rise_taus[4]  = {5.0f, 20.0f, 10.0f, 2.0f};

typedef float v2f __attribute__((ext_vector_type(2)));

// Per-row stats, 32 B.
struct alignas(16) RowStat {
    unsigned nSk;   // n | (Sk<<16)
    unsigned Skk;
    float    csum;
    unsigned pki;   // (peak<<22)|(i10<<11)|i90
    double   Sy;
    double   Sky;
};

// ---- DPP wave-reduction helpers (pure VALU, no DS unit) ----
template<int CTRL>
__device__ __forceinline__ unsigned dpp0_u32(unsigned x) {
    return (unsigned)__builtin_amdgcn_update_dpp(0, (int)x, CTRL, 0xf, 0xf, true);
}
template<int CTRL>
__device__ __forceinline__ float dpp0_f32(float x) {
    return __int_as_float(
        __builtin_amdgcn_update_dpp(0, __float_as_int(x), CTRL, 0xf, 0xf, true));
}
template<int CTRL>
__device__ __forceinline__ float dppid_f32(float x) {
    return __int_as_float(__builtin_amdgcn_update_dpp(
        __float_as_int(x), __float_as_int(x), CTRL, 0xf, 0xf, false));
}
template<int CTRL>
__device__ __forceinline__ double dpp0_f64(double x) {
    const int lo = __builtin_amdgcn_update_dpp(0, __double2loint(x), CTRL, 0xf, 0xf, true);
    const int hi = __builtin_amdgcn_update_dpp(0, __double2hiint(x), CTRL, 0xf, 0xf, true);
    return __hiloint2double(hi, lo);
}
#define ROW_SHR1  0x111
#define ROW_SHR2  0x112
#define ROW_SHR4  0x114
#define ROW_SHR8  0x118
#define BCAST15   0x142
#define BCAST31   0x143
#define WSUM_F32(x) { x += dpp0_f32<ROW_SHR1>(x); x += dpp0_f32<ROW_SHR2>(x); \
                      x += dpp0_f32<ROW_SHR4>(x); x += dpp0_f32<ROW_SHR8>(x); \
                      x += dpp0_f32<BCAST15>(x);  x += dpp0_f32<BCAST31>(x); }
#define WSUM_U32(x) { x += dpp0_u32<ROW_SHR1>(x); x += dpp0_u32<ROW_SHR2>(x); \
                      x += dpp0_u32<ROW_SHR4>(x); x += dpp0_u32<ROW_SHR8>(x); \
                      x += dpp0_u32<BCAST15>(x);  x += dpp0_u32<BCAST31>(x); }
#define WSUM_F64(x) { x += dpp0_f64<ROW_SHR1>(x); x += dpp0_f64<ROW_SHR2>(x); \
                      x += dpp0_f64<ROW_SHR4>(x); x += dpp0_f64<ROW_SHR8>(x); \
                      x += dpp0_f64<BCAST15>(x);  x += dpp0_f64<BCAST31>(x); }
#define WMAX_F32(x) { x = fmaxf(x, dppid_f32<ROW_SHR1>(x)); x = fmaxf(x, dppid_f32<ROW_SHR2>(x)); \
                      x = fmaxf(x, dppid_f32<ROW_SHR4>(x)); x = fmaxf(x, dppid_f32<ROW_SHR8>(x)); \
                      x = fmaxf(x, dppid_f32<BCAST15>(x));  x = fmaxf(x, dppid_f32<BCAST31>(x)); }

// Kernel 1: waveform-only, one row per wave. DPP reductions, ballot index
// finding, closed-form n/Sk/Skk (ballot-popcount-verified) with exact cold
// fallback. NOTE: keep this kernel free of any extra side-effects/parameters —
// adding an atomic store at entry (r11) or fusing the reduction tail (r6/r10)
// collapses hipcc regalloc to 24-32 VGPR and serializes the loads (7x slower).
// Also: ballots (v_cmp+SALU) beat per-lane DPP index-min here (r14, -11%) —
// the scalar pipe runs concurrently with VALU.
extern "C" __global__ __launch_bounds__(256, 8)
void physics_rows(const float* __restrict__ wave, RowStat* __restrict__ stats)
{
    const int lane = threadIdx.x & 63;
    const int row  = (blockIdx.x * 256 + (int)threadIdx.x) >> 6;   // 1 row per wave
    const int lane4 = lane * 4;
    const float4* p = reinterpret_cast<const float4*>(wave) + (size_t)row * (SLEN / 4) + lane;

    const float4 c0 = p[0], c1 = p[64], c2 = p[128], c3 = p[192];
    float vals[16] = {c0.x,c0.y,c0.z,c0.w, c1.x,c1.y,c1.z,c1.w,
                      c2.x,c2.y,c2.z,c2.w, c3.x,c3.y,c3.z,c3.w};

    // ---- pass 1: per-lane value-max (max3 tree) + relu-sum (packed f32) ----
    float m0 = fmaxf(fmaxf(vals[0],  vals[1]),  vals[2]);
    float m1 = fmaxf(fmaxf(vals[3],  vals[4]),  vals[5]);
    float m2 = fmaxf(fmaxf(vals[6],  vals[7]),  vals[8]);
    float m3 = fmaxf(fmaxf(vals[9],  vals[10]), vals[11]);
    float m4 = fmaxf(fmaxf(vals[12], vals[13]), fmaxf(vals[14], vals[15]));
    float bm = fmaxf(fmaxf(fmaxf(m0, m1), m2), fmaxf(m3, m4));

    v2f sa = {0.f, 0.f}, sb = {0.f, 0.f};
    #pragma unroll
    for (int k = 0; k < 16; k += 4) {
        v2f p0 = {vals[k],     vals[k + 1]};
        v2f p1 = {vals[k + 2], vals[k + 3]};
        sa += __builtin_elementwise_max(p0, (v2f){0.f, 0.f});
        sb += __builtin_elementwise_max(p1, (v2f){0.f, 0.f});
    }
    const v2f sab = sa + sb;
    float csum = sab.x + sab.y;

    // ---- DPP wave reductions: amp (max) + csum (sum, valid lane 63) ----
    WMAX_F32(bm);
    WSUM_F32(csum);
    const float amp = __int_as_float(
        __builtin_amdgcn_readlane(__float_as_int(bm), 63));

    // ---- peak = first index with w == amp (ballot + uniform SALU, early exit) ----
    int peak = SLEN;
    #pragma unroll
    for (int q = 0; q < 4; ++q) {
        bool found = false;
        #pragma unroll
        for (int r = 0; r < 4; ++r) {
            const unsigned long long b = __ballot(vals[q * 4 + r] == amp);
            if (b) {
                peak = min(peak, q * 256 + 4 * (__ffsll(b) - 1) + r);
                found = true;
            }
        }
        if (found) break;
    }
    peak = __builtin_amdgcn_readfirstlane(peak);
    const bool do_decay = (peak < SLEN - 20);
    const int  pm5 = peak + 5;

    // ---- rise crossings: unmasked ballots, quarter-at-a-time uniform scan ----
    const float t10v = 0.1f * amp, t90v = 0.9f * amp;
    int i10 = SLEN, i90 = SLEN;
    const int q_peak = peak >> 8;
    #pragma unroll
    for (int q = 0; q < 4; ++q) {
        if (q > q_peak || (i10 < SLEN && i90 < SLEN)) break;   // uniform
        const int qb = q * 256;
        unsigned long long m10[4], m90[4];
        #pragma unroll
        for (int r = 0; r < 4; ++r) {
            m10[r] = __ballot(vals[q * 4 + r] >= t10v);
            m90[r] = __ballot(vals[q * 4 + r] >= t90v);
        }
        if (q == q_peak) {                 // boundary quarter: mask to j < peak
            #pragma unroll
            for (int r = 0; r < 4; ++r) {
                const int cnt = (peak - qb - r + 3) >> 2;
                const unsigned long long lm =
                    (cnt >= 64) ? ~0ull : ((cnt <= 0) ? 0ull : ((1ull << cnt) - 1ull));
                m10[r] &= lm; m90[r] &= lm;
            }
        }
        if (i10 == SLEN) {
            int best = SLEN;
            #pragma unroll
            for (int r = 0; r < 4; ++r)
                if (m10[r]) best = min(best, qb + 4 * (__ffsll(m10[r]) - 1) + r);
            i10 = best;
        }
        if (i90 == SLEN) {
            int best = SLEN;
            #pragma unroll
            for (int r = 0; r < 4; ++r)
                if (m90[r]) best = min(best, qb + 4 * (__ffsll(m90[r]) - 1) + r);
            i90 = best;
        }
    }

    // ---- decay: f64 y-sums per element; n/Sk/Skk closed-form (verified) ----
    double Sy = 0.0, Sky = 0.0;
    int cnt = 0;                           // wave-uniform (ballot popcounts)
    if (do_decay) {                        // uniform
        #pragma unroll
        for (int q = 0; q < 4; ++q) {
            if (q * 256 + 255 >= pm5 && q * 256 <= pm5 + (TAILW - 1)) {  // uniform
                #pragma unroll
                for (int r = 0; r < 4; ++r) {
                    const int kk = q * 256 + lane4 + r - pm5;
                    const float w = vals[q * 4 + r];
                    const bool cond = ((unsigned)kk < (unsigned)TAILW) && (w > 0.0f);
                    const float ym = cond ? __logf(w + 1e-8f) : 0.0f;  // native log
                    cnt += (int)__popcll(__ballot(cond));
                    const double y64 = (double)ym;     // masked lanes add +0.0
                    Sy += y64;
                    Sky = fma((double)kk, y64, Sky);
                }
            }
        }
    }
    WSUM_F64(Sy);
    WSUM_F64(Sky);

    // n/Sk/Skk: closed form when all L window samples positive (cnt==L)
    unsigned out_nSk = 0, out_Skk = 0;
    if (do_decay) {
        const int L = min(TAILW, SLEN - pm5);
        if (cnt == (int)L) {               // common case: uniform SALU math
            const unsigned uL = (unsigned)L;
            const unsigned Sk = uL * (uL - 1u) / 2u;
            out_nSk = uL | (Sk << 16);
            out_Skk = (uL - 1u) * uL * (2u * uL - 1u) / 6u;
        } else {                           // rare (exact zeros in tail): recompute
            unsigned nSk_p = 0, Skk = 0;
            #pragma unroll
            for (int q = 0; q < 4; ++q) {
                if (q * 256 + 255 >= pm5 && q * 256 <= pm5 + (TAILW - 1)) {
                    #pragma unroll
                    for (int r = 0; r < 4; ++r) {
                        const int kk = q * 256 + lane4 + r - pm5;
                        const float w = vals[q * 4 + r];
                        if (((unsigned)kk < (unsigned)TAILW) && (w > 0.0f)) {
                            nSk_p += 1u + ((unsigned)kk << 8);
                            Skk   += (unsigned)(kk * kk);
                        }
                    }
                }
            }
            WSUM_U32(nSk_p);
            WSUM_U32(Skk);
            out_nSk = (nSk_p & 0xFFu) | ((nSk_p >> 8) << 16);  // valid in lane 63
            out_Skk = Skk;
        }
    }

    if (lane == 63) {
        RowStat st;
        st.nSk  = out_nSk;
        st.Skk  = out_Skk;
        st.csum = csum;
        st.pki  = ((unsigned)peak << 22) | ((unsigned)i10 << 11) | (unsigned)i90;
        st.Sy   = Sy;
        st.Sky  = Sky;
        stats[row] = st;
    }
}

// Kernel 2: one thread per row epilogue (256 blocks x 128 threads -> all CUs
// busy) + block partials + last-block final reduce (atomic-counter pattern).
extern "C" __global__ __launch_bounds__(128)
void physics_rowfin(const RowStat* __restrict__ stats,
                    const float* __restrict__ logits,
                    const int* __restrict__ labels,
                    const float* __restrict__ amps,
                    double* __restrict__ partials,     // [7][PSTRIDE]
                    unsigned* __restrict__ counter,    // zeroed by memset each launch
                    float* __restrict__ out)
{
    const int r    = blockIdx.x * 128 + threadIdx.x;   // always < BROWS
    const int lane = threadIdx.x & 63;
    const int wid  = threadIdx.x >> 6;                 // 0..1

    __shared__ double sm[2][7];
    __shared__ int s_last;

    const RowStat st = stats[r];
    const unsigned n_u  = st.nSk & 0xFFFFu;
    const unsigned Sk_u = st.nSk >> 16;
    const int peak = (int)(st.pki >> 22);
    const int i10  = (int)((st.pki >> 11) & 0x7FFu);
    const int i90  = (int)(st.pki & 0x7FFu);

    // CE + predicted class (library expf/logf — accuracy matters here)
    const float4 l4 = reinterpret_cast<const float4*>(logits)[r];
    float lg[4] = {l4.x, l4.y, l4.z, l4.w};
    int pred = 0; float pbest = lg[0];
    #pragma unroll
    for (int c = 1; c < 4; ++c) if (lg[c] > pbest) { pbest = lg[c]; pred = c; }
    const float m = fmaxf(fmaxf(lg[0], lg[1]), fmaxf(lg[2], lg[3]));
    const float sexp = expf(lg[0] - m) + expf(lg[1] - m)
                     + expf(lg[2] - m) + expf(lg[3] - m);
    const float lse = m + logf(sexp);
    const double v0 = (double)(lse - lg[labels[r]]);

    // decay loss (f64 combine — slope/tau cancellation-sensitive)
    double v1 = 0.0, v2 = 0.0;
    if (peak < SLEN - 20 && n_u >= 5u) {
        const double dn  = (double)n_u;
        const double dSk = (double)Sk_u;
        const double num = st.Sky - dSk * st.Sy / dn;           // DT_NS factored out
        const double den = 8.0 * ((double)st.Skk - dSk * dSk / dn);
        if (den > 0.0) {
            const double slope = num / fmax(den, 1e-30);
            const double tau   = -1.0 / (slope + 1e-8);
            const double d     = tau - (double)c_decay_taus[pred];
            v1 = d * d; v2 = 1.0;
        }
    }
    // rise loss
    double v3 = 0.0, v4 = 0.0;
    if (peak >= 10 && i10 < SLEN && i90 < SLEN) {
        const float rise = (float)(i90 - i10) * 8.0f;
        const float er   = c_rise_taus[pred];
        v3 = (double)(fabsf(rise - er) / er); v4 = 1.0;
    }
    // energy ratio moments
    const double ratio = (double)st.csum / ((double)amps[r] + 1e-8);

    double v[7] = {v0, v1, v2, v3, v4, ratio, ratio * ratio};
    #pragma unroll
    for (int i = 0; i < 7; ++i) {
        #pragma unroll
        for (int off = 1; off < 64; off <<= 1)
            v[i] += __shfl_xor(v[i], off, 64);
    }
    if (lane == 0) {
        #pragma unroll
        for (int i = 0; i < 7; ++i) sm[wid][i] = v[i];
    }
    __syncthreads();
    if (threadIdx.x < 7) {
        const int i = threadIdx.x;
        const double t = sm[0][i] + sm[1][i];
        __hip_atomic_store(&partials[(size_t)i * PSTRIDE + blockIdx.x], t,
                           __ATOMIC_RELAXED, __HIP_MEMORY_SCOPE_AGENT);
    }
    __syncthreads();
    if (threadIdx.x == 0) {
        const unsigned prev = __hip_atomic_fetch_add(counter, 1u,
                                  __ATOMIC_ACQ_REL, __HIP_MEMORY_SCOPE_AGENT);
        s_last = (prev == NB2 - 1) ? 1 : 0;
    }
    __syncthreads();
    if (!s_last) return;

    // ---- last block: reduce [7][256] partials, write the 5 outputs ----
    double loc[7];
    #pragma unroll
    for (int i = 0; i < 7; ++i) {
        loc[i] = __hip_atomic_load(&partials[(size_t)i * PSTRIDE + threadIdx.x],
                                   __ATOMIC_RELAXED, __HIP_MEMORY_SCOPE_AGENT)
               + __hip_atomic_load(&partials[(size_t)i * PSTRIDE + threadIdx.x + 128],
                                   __ATOMIC_RELAXED, __HIP_MEMORY_SCOPE_AGENT);
    }
    #pragma unroll
    for (int i = 0; i < 7; ++i) {
        #pragma unroll
        for (int off = 1; off < 64; off <<= 1)
            loc[i] += __shfl_xor(loc[i], off, 64);
    }
    __syncthreads();                       // reuse sm safely
    if (lane == 0) {
        #pragma unroll
        for (int i = 0; i < 7; ++i) sm[wid][i] = loc[i];
    }
    __syncthreads();
    if (threadIdx.x == 0) {
        double t[7];
        #pragma unroll
        for (int i = 0; i < 7; ++i) t[i] = sm[0][i] + sm[1][i];
        const double Bn = (double)BROWS;
        const double ce    = t[0] / Bn;
        const double decay = (t[2] > 0.0) ? t[1] / fmax(t[2], 1.0) : 0.0;
        const double rise  = (t[4] > 0.0) ? t[3] / fmax(t[4], 1.0) : 0.0;
        const double var   = (t[6] - t[5] * t[5] / Bn) / (Bn - 1.0);  // ddof=1
        const double total = 0.7 * ce + 0.2 * decay + 0.1 * var + 0.05 * rise;
        out[0] = (float)total; out[1] = (float)ce; out[2] = (float)decay;
        out[3] = (float)var;   out[4] = (float)rise;
    }
}

extern "C" void kernel_launch(void* const* d_in, const int* in_sizes, int n_in,
                              void* d_out, int out_size, void* d_ws, size_t ws_size,
                              hipStream_t stream) {
    const float* logits = (const float*)d_in[0];
    const int*   labels = (const int*)d_in[1];
    const float* wave   = (const float*)d_in[2];
    const float* amps   = (const float*)d_in[3];

    RowStat*  stats    = (RowStat*)d_ws;                                  // 1 MiB
    double*   partials = (double*)((char*)d_ws + (size_t)BROWS * sizeof(RowStat));
    unsigned* counter  = (unsigned*)((char*)partials + 7 * PSTRIDE * sizeof(double));

    hipMemsetAsync(counter, 0, sizeof(unsigned), stream);
    physics_rows<<<NB1, 256, 0, stream>>>(wave, stats);
    physics_rowfin<<<NB2, 128, 0, stream>>>(stats, logits, labels, amps,
                                            partials, counter, (float*)d_out);
}

// Round 16
// 39.695 us; speedup vs baseline: 1.1111x; 1.0376x over previous
//
#include <hip/hip_runtime.h>
#include <cmath>

// Problem constants
#define BROWS 32768
#define SLEN  1024
#define TAILW 195
#define NB1   8192            // rows kernel: 8192 blocks x 4 waves = 32768 waves, 1 row/wave
#define NB2   128             // rowfin: 128 blocks x 256 threads, 1 row/thread
#define PSTRIDE 128           // partials [7][128]

__device__ __constant__ float c_decay_taus[4] = {40.0f, 300.0f, 230.0f, 2.4f};
__device__ __constant__ float c_rise_taus[4]  = {5.0f, 20.0f, 10.0f, 2.0f};

typedef float v2f __attribute__((ext_vector_type(2)));

// Per-row stats, 32 B.
struct alignas(16) RowStat {
    unsigned nSk;   // n | (Sk<<16)
    unsigned Skk;
    float    csum;
    unsigned pki;   // (peak<<22)|(i10<<11)|i90
    double   Sy;
    double   Sky;
};

// ---- DPP wave-reduction helpers (pure VALU, no DS unit) ----
template<int CTRL>
__device__ __forceinline__ unsigned dpp0_u32(unsigned x) {
    return (unsigned)__builtin_amdgcn_update_dpp(0, (int)x, CTRL, 0xf, 0xf, true);
}
template<int CTRL>
__device__ __forceinline__ float dpp0_f32(float x) {
    return __int_as_float(
        __builtin_amdgcn_update_dpp(0, __float_as_int(x), CTRL, 0xf, 0xf, true));
}
template<int CTRL>
__device__ __forceinline__ float dppid_f32(float x) {
    return __int_as_float(__builtin_amdgcn_update_dpp(
        __float_as_int(x), __float_as_int(x), CTRL, 0xf, 0xf, false));
}
template<int CTRL>
__device__ __forceinline__ double dpp0_f64(double x) {
    const int lo = __builtin_amdgcn_update_dpp(0, __double2loint(x), CTRL, 0xf, 0xf, true);
    const int hi = __builtin_amdgcn_update_dpp(0, __double2hiint(x), CTRL, 0xf, 0xf, true);
    return __hiloint2double(hi, lo);
}
#define ROW_SHR1  0x111
#define ROW_SHR2  0x112
#define ROW_SHR4  0x114
#define ROW_SHR8  0x118
#define BCAST15   0x142
#define BCAST31   0x143
#define WSUM_F32(x) { x += dpp0_f32<ROW_SHR1>(x); x += dpp0_f32<ROW_SHR2>(x); \
                      x += dpp0_f32<ROW_SHR4>(x); x += dpp0_f32<ROW_SHR8>(x); \
                      x += dpp0_f32<BCAST15>(x);  x += dpp0_f32<BCAST31>(x); }
#define WSUM_U32(x) { x += dpp0_u32<ROW_SHR1>(x); x += dpp0_u32<ROW_SHR2>(x); \
                      x += dpp0_u32<ROW_SHR4>(x); x += dpp0_u32<ROW_SHR8>(x); \
                      x += dpp0_u32<BCAST15>(x);  x += dpp0_u32<BCAST31>(x); }
#define WSUM_F64(x) { x += dpp0_f64<ROW_SHR1>(x); x += dpp0_f64<ROW_SHR2>(x); \
                      x += dpp0_f64<ROW_SHR4>(x); x += dpp0_f64<ROW_SHR8>(x); \
                      x += dpp0_f64<BCAST15>(x);  x += dpp0_f64<BCAST31>(x); }
#define WMAX_F32(x) { x = fmaxf(x, dppid_f32<ROW_SHR1>(x)); x = fmaxf(x, dppid_f32<ROW_SHR2>(x)); \
                      x = fmaxf(x, dppid_f32<ROW_SHR4>(x)); x = fmaxf(x, dppid_f32<ROW_SHR8>(x)); \
                      x = fmaxf(x, dppid_f32<BCAST15>(x));  x = fmaxf(x, dppid_f32<BCAST31>(x)); }

// Kernel 1: waveform-only, one row per wave. DPP reductions, ballot index
// finding, closed-form n/Sk/Skk (ballot-popcount-verified) with exact cold
// fallback. NOTE: keep this kernel free of any extra side-effects/parameters —
// adding an atomic store at entry (r11) or fusing the reduction tail (r6/r10)
// collapses hipcc regalloc to 24-32 VGPR and serializes the loads (7x slower).
// Also: ballots (v_cmp+SALU) beat per-lane DPP index-min here (r14, -11%) —
// the scalar pipe runs concurrently with VALU.
extern "C" __global__ __launch_bounds__(256, 8)
void physics_rows(const float* __restrict__ wave, RowStat* __restrict__ stats)
{
    const int lane = threadIdx.x & 63;
    const int row  = (blockIdx.x * 256 + (int)threadIdx.x) >> 6;   // 1 row per wave
    const int lane4 = lane * 4;
    const float4* p = reinterpret_cast<const float4*>(wave) + (size_t)row * (SLEN / 4) + lane;

    const float4 c0 = p[0], c1 = p[64], c2 = p[128], c3 = p[192];
    float vals[16] = {c0.x,c0.y,c0.z,c0.w, c1.x,c1.y,c1.z,c1.w,
                      c2.x,c2.y,c2.z,c2.w, c3.x,c3.y,c3.z,c3.w};

    // ---- pass 1: per-lane value-max (max3 tree) + relu-sum (packed f32) ----
    float m0 = fmaxf(fmaxf(vals[0],  vals[1]),  vals[2]);
    float m1 = fmaxf(fmaxf(vals[3],  vals[4]),  vals[5]);
    float m2 = fmaxf(fmaxf(vals[6],  vals[7]),  vals[8]);
    float m3 = fmaxf(fmaxf(vals[9],  vals[10]), vals[11]);
    float m4 = fmaxf(fmaxf(vals[12], vals[13]), fmaxf(vals[14], vals[15]));
    float bm = fmaxf(fmaxf(fmaxf(m0, m1), m2), fmaxf(m3, m4));

    v2f sa = {0.f, 0.f}, sb = {0.f, 0.f};
    #pragma unroll
    for (int k = 0; k < 16; k += 4) {
        v2f p0 = {vals[k],     vals[k + 1]};
        v2f p1 = {vals[k + 2], vals[k + 3]};
        sa += __builtin_elementwise_max(p0, (v2f){0.f, 0.f});
        sb += __builtin_elementwise_max(p1, (v2f){0.f, 0.f});
    }
    const v2f sab = sa + sb;
    float csum = sab.x + sab.y;

    // ---- DPP wave reductions: amp (max) + csum (sum, valid lane 63) ----
    WMAX_F32(bm);
    WSUM_F32(csum);
    const float amp = __int_as_float(
        __builtin_amdgcn_readlane(__float_as_int(bm), 63));

    // ---- peak = first index with w == amp (ballot + uniform SALU, early exit) ----
    int peak = SLEN;
    #pragma unroll
    for (int q = 0; q < 4; ++q) {
        bool found = false;
        #pragma unroll
        for (int r = 0; r < 4; ++r) {
            const unsigned long long b = __ballot(vals[q * 4 + r] == amp);
            if (b) {
                peak = min(peak, q * 256 + 4 * (__ffsll(b) - 1) + r);
                found = true;
            }
        }
        if (found) break;
    }
    peak = __builtin_amdgcn_readfirstlane(peak);
    const bool do_decay = (peak < SLEN - 20);
    const int  pm5 = peak + 5;

    // ---- rise crossings: unmasked ballots, quarter-at-a-time uniform scan ----
    const float t10v = 0.1f * amp, t90v = 0.9f * amp;
    int i10 = SLEN, i90 = SLEN;
    const int q_peak = peak >> 8;
    #pragma unroll
    for (int q = 0; q < 4; ++q) {
        if (q > q_peak || (i10 < SLEN && i90 < SLEN)) break;   // uniform
        const int qb = q * 256;
        unsigned long long m10[4], m90[4];
        #pragma unroll
        for (int r = 0; r < 4; ++r) {
            m10[r] = __ballot(vals[q * 4 + r] >= t10v);
            m90[r] = __ballot(vals[q * 4 + r] >= t90v);
        }
        if (q == q_peak) {                 // boundary quarter: mask to j < peak
            #pragma unroll
            for (int r = 0; r < 4; ++r) {
                const int cnt = (peak - qb - r + 3) >> 2;
                const unsigned long long lm =
                    (cnt >= 64) ? ~0ull : ((cnt <= 0) ? 0ull : ((1ull << cnt) - 1ull));
                m10[r] &= lm; m90[r] &= lm;
            }
        }
        if (i10 == SLEN) {
            int best = SLEN;
            #pragma unroll
            for (int r = 0; r < 4; ++r)
                if (m10[r]) best = min(best, qb + 4 * (__ffsll(m10[r]) - 1) + r);
            i10 = best;
        }
        if (i90 == SLEN) {
            int best = SLEN;
            #pragma unroll
            for (int r = 0; r < 4; ++r)
                if (m90[r]) best = min(best, qb + 4 * (__ffsll(m90[r]) - 1) + r);
            i90 = best;
        }
    }

    // ---- decay: f64 y-sums per element; n/Sk/Skk closed-form (verified) ----
    double Sy = 0.0, Sky = 0.0;
    int cnt = 0;                           // wave-uniform (ballot popcounts)
    if (do_decay) {                        // uniform
        #pragma unroll
        for (int q = 0; q < 4; ++q) {
            if (q * 256 + 255 >= pm5 && q * 256 <= pm5 + (TAILW - 1)) {  // uniform
                #pragma unroll
                for (int r = 0; r < 4; ++r) {
                    const int kk = q * 256 + lane4 + r - pm5;
                    const float w = vals[q * 4 + r];
                    const bool cond = ((unsigned)kk < (unsigned)TAILW) && (w > 0.0f);
                    const float ym = cond ? __logf(w + 1e-8f) : 0.0f;  // native log
                    cnt += (int)__popcll(__ballot(cond));
                    const double y64 = (double)ym;     // masked lanes add +0.0
                    Sy += y64;
                    Sky = fma((double)kk, y64, Sky);
                }
            }
        }
    }
    WSUM_F64(Sy);
    WSUM_F64(Sky);

    // n/Sk/Skk: closed form when all L window samples positive (cnt==L)
    unsigned out_nSk = 0, out_Skk = 0;
    if (do_decay) {
        const int L = min(TAILW, SLEN - pm5);
        if (cnt == (int)L) {               // common case: uniform SALU math
            const unsigned uL = (unsigned)L;
            const unsigned Sk = uL * (uL - 1u) / 2u;
            out_nSk = uL | (Sk << 16);
            out_Skk = (uL - 1u) * uL * (2u * uL - 1u) / 6u;
        } else {                           // rare (exact zeros in tail): recompute
            unsigned nSk_p = 0, Skk = 0;
            #pragma unroll
            for (int q = 0; q < 4; ++q) {
                if (q * 256 + 255 >= pm5 && q * 256 <= pm5 + (TAILW - 1)) {
                    #pragma unroll
                    for (int r = 0; r < 4; ++r) {
                        const int kk = q * 256 + lane4 + r - pm5;
                        const float w = vals[q * 4 + r];
                        if (((unsigned)kk < (unsigned)TAILW) && (w > 0.0f)) {
                            nSk_p += 1u + ((unsigned)kk << 8);
                            Skk   += (unsigned)(kk * kk);
                        }
                    }
                }
            }
            WSUM_U32(nSk_p);
            WSUM_U32(Skk);
            out_nSk = (nSk_p & 0xFFu) | ((nSk_p >> 8) << 16);  // valid in lane 63
            out_Skk = Skk;
        }
    }

    if (lane == 63) {
        RowStat st;
        st.nSk  = out_nSk;
        st.Skk  = out_Skk;
        st.csum = csum;
        st.pki  = ((unsigned)peak << 22) | ((unsigned)i10 << 11) | (unsigned)i90;
        st.Sy   = Sy;
        st.Sky  = Sky;
        stats[row] = st;
    }
}

// Kernel 2: one thread per row epilogue + block partials + last-block final
// reduce (atomic-counter pattern).
extern "C" __global__ __launch_bounds__(256)
void physics_rowfin(const RowStat* __restrict__ stats,
                    const float* __restrict__ logits,
                    const int* __restrict__ labels,
                    const float* __restrict__ amps,
                    double* __restrict__ partials,     // [7][PSTRIDE]
                    unsigned* __restrict__ counter,    // zeroed by memset each launch
                    float* __restrict__ out)
{
    const int r    = blockIdx.x * 256 + threadIdx.x;   // always < BROWS
    const int lane = threadIdx.x & 63;
    const int wid  = threadIdx.x >> 6;

    __shared__ double sm[4][7];
    __shared__ int s_last;

    const RowStat st = stats[r];
    const unsigned n_u  = st.nSk & 0xFFFFu;
    const unsigned Sk_u = st.nSk >> 16;
    const int peak = (int)(st.pki >> 22);
    const int i10  = (int)((st.pki >> 11) & 0x7FFu);
    const int i90  = (int)(st.pki & 0x7FFu);

    // CE + predicted class (library expf/logf — accuracy matters here)
    const float4 l4 = reinterpret_cast<const float4*>(logits)[r];
    float lg[4] = {l4.x, l4.y, l4.z, l4.w};
    int pred = 0; float pbest = lg[0];
    #pragma unroll
    for (int c = 1; c < 4; ++c) if (lg[c] > pbest) { pbest = lg[c]; pred = c; }
    const float m = fmaxf(fmaxf(lg[0], lg[1]), fmaxf(lg[2], lg[3]));
    const float sexp = expf(lg[0] - m) + expf(lg[1] - m)
                     + expf(lg[2] - m) + expf(lg[3] - m);
    const float lse = m + logf(sexp);
    const double v0 = (double)(lse - lg[labels[r]]);

    // decay loss (f64 combine — slope/tau cancellation-sensitive)
    double v1 = 0.0, v2 = 0.0;
    if (peak < SLEN - 20 && n_u >= 5u) {
        const double dn  = (double)n_u;
        const double dSk = (double)Sk_u;
        const double num = st.Sky - dSk * st.Sy / dn;           // DT_NS factored out
        const double den = 8.0 * ((double)st.Skk - dSk * dSk / dn);
        if (den > 0.0) {
            const double slope = num / fmax(den, 1e-30);
            const double tau   = -1.0 / (slope + 1e-8);
            const double d     = tau - (double)c_decay_taus[pred];
            v1 = d * d; v2 = 1.0;
        }
    }
    // rise loss
    double v3 = 0.0, v4 = 0.0;
    if (peak >= 10 && i10 < SLEN && i90 < SLEN) {
        const float rise = (float)(i90 - i10) * 8.0f;
        const float er   = c_rise_taus[pred];
        v3 = (double)(fabsf(rise - er) / er); v4 = 1.0;
    }
    // energy ratio moments
    const double ratio = (double)st.csum / ((double)amps[r] + 1e-8);

    double v[7] = {v0, v1, v2, v3, v4, ratio, ratio * ratio};
    #pragma unroll
    for (int i = 0; i < 7; ++i) {
        #pragma unroll
        for (int off = 1; off < 64; off <<= 1)
            v[i] += __shfl_xor(v[i], off, 64);
    }
    if (lane == 0) {
        #pragma unroll
        for (int i = 0; i < 7; ++i) sm[wid][i] = v[i];
    }
    __syncthreads();
    if (threadIdx.x < 7) {
        const int i = threadIdx.x;
        const double t = sm[0][i] + sm[1][i] + sm[2][i] + sm[3][i];
        __hip_atomic_store(&partials[(size_t)i * PSTRIDE + blockIdx.x], t,
                           __ATOMIC_RELAXED, __HIP_MEMORY_SCOPE_AGENT);
    }
    __syncthreads();
    if (threadIdx.x == 0) {
        const unsigned prev = __hip_atomic_fetch_add(counter, 1u,
                                  __ATOMIC_ACQ_REL, __HIP_MEMORY_SCOPE_AGENT);
        s_last = (prev == NB2 - 1) ? 1 : 0;
    }
    __syncthreads();
    if (!s_last) return;

    // ---- last block: reduce [7][128] partials, write the 5 outputs ----
    double loc[7] = {0, 0, 0, 0, 0, 0, 0};
    if (threadIdx.x < PSTRIDE) {
        #pragma unroll
        for (int i = 0; i < 7; ++i)
            loc[i] = __hip_atomic_load(&partials[(size_t)i * PSTRIDE + threadIdx.x],
                                       __ATOMIC_RELAXED, __HIP_MEMORY_SCOPE_AGENT);
    }
    #pragma unroll
    for (int i = 0; i < 7; ++i) {
        #pragma unroll
        for (int off = 1; off < 64; off <<= 1)
            loc[i] += __shfl_xor(loc[i], off, 64);
    }
    __syncthreads();                       // reuse sm safely
    if (lane == 0 && wid < 2) {
        #pragma unroll
        for (int i = 0; i < 7; ++i) sm[wid][i] = loc[i];
    }
    __syncthreads();
    if (threadIdx.x == 0) {
        double t[7];
        #pragma unroll
        for (int i = 0; i < 7; ++i) t[i] = sm[0][i] + sm[1][i];
        const double Bn = (double)BROWS;
        const double ce    = t[0] / Bn;
        const double decay = (t[2] > 0.0) ? t[1] / fmax(t[2], 1.0) : 0.0;
        const double rise  = (t[4] > 0.0) ? t[3] / fmax(t[4], 1.0) : 0.0;
        const double var   = (t[6] - t[5] * t[5] / Bn) / (Bn - 1.0);  // ddof=1
        const double total = 0.7 * ce + 0.2 * decay + 0.1 * var + 0.05 * rise;
        out[0] = (float)total; out[1] = (float)ce; out[2] = (float)decay;
        out[3] = (float)var;   out[4] = (float)rise;
    }
}

extern "C" void kernel_launch(void* const* d_in, const int* in_sizes, int n_in,
                              void* d_out, int out_size, void* d_ws, size_t ws_size,
                              hipStream_t stream) {
    const float* logits = (const float*)d_in[0];
    const int*   labels = (const int*)d_in[1];
    const float* wave   = (const float*)d_in[2];
    const float* amps   = (const float*)d_in[3];

    RowStat*  stats    = (RowStat*)d_ws;                                  // 1 MiB
    double*   partials = (double*)((char*)d_ws + (size_t)BROWS * sizeof(RowStat));
    unsigned* counter  = (unsigned*)((char*)partials + 7 * PSTRIDE * sizeof(double));

    hipMemsetAsync(counter, 0, sizeof(unsigned), stream);
    physics_rows<<<NB1, 256, 0, stream>>>(wave, stats);
    physics_rowfin<<<NB2, 256, 0, stream>>>(stats, logits, labels, amps,
                                            partials, counter, (float*)d_out);
}